// Round 11
// baseline (3847.645 us; speedup 1.0000x reference)
//
#include <hip/hip_runtime.h>
#include <cstddef>

// ---------------------------------------------------------------------------
// RQ-VAE forward on MI355X. Round 11: scalar-path codes/weights.
// R10 post-mortem: rvq scan is LDS-ISSUE-bound (W waves multiply ds_read
// cycles, not VALU): 4 waves -> 384 LDS cyc vs 128 VALU cyc per code. Fix:
// code addresses are wave-uniform -> read via scalar cache (s_load), no LDS.
// Same for conv weights (block-uniform oc0): drop LDS staging.
// rvq3 numerics = verbatim from validated kernels (R2 full-lane layout,
// R7 norm table, fmaf(-2,dot,sr2)+c2, strict <).
// ---------------------------------------------------------------------------

template<int ACT> __device__ __forceinline__ float actf(float v) {
    if constexpr (ACT == 1) return v > 0.f ? v : 0.f;            // relu
    else if constexpr (ACT == 2) return v > 0.f ? v : 0.01f * v; // leaky relu
    else return v;
}
__device__ __forceinline__ float lrelu_in(float v) { return v > 0.f ? v : 0.01f * v; }

// ---------------------------------------------------------------------------
// Direct conv (LDS-staged weights): used for e1/e2 (K=4,S=2). (validated R8)
// ---------------------------------------------------------------------------
template<int CIN, int COUT, int K, int S, int P, int HIN, int WIN, int HOUT, int WOUT,
         int ICC, int NPY, int ACT, bool BIAS>
__launch_bounds__(256, (NPY >= 4 ? 2 : 4))
__global__ void conv_k(const float* __restrict__ in, const float* __restrict__ w,
                       const float* __restrict__ bias, float* __restrict__ out)
{
    constexpr int K2 = K * K;
    constexpr int NR = S * (NPY - 1) + K;
    constexpr int BH = 16 * NPY;
    __shared__ float sw[ICC * K2 * 16];
    const int tid = threadIdx.x;
    const int tx = tid & 15, ty = tid >> 4;
    constexpr int TW = WOUT / 16;
    const int bx = blockIdx.x % TW, by = blockIdx.x / TW;
    const int ox = bx * 16 + tx;
    const int oy0 = by * BH + ty * NPY;
    const int oc0 = blockIdx.y * 16;
    const int n = blockIdx.z;
    const int ix0 = ox * S - P, iy0 = oy0 * S - P;

    int ro[NR]; float mr[NR];
#pragma unroll
    for (int r = 0; r < NR; ++r) {
        const int iy = iy0 + r;
        const bool v = (iy >= 0) && (iy < HIN);
        ro[r] = v ? iy * WIN : 0;
        mr[r] = v ? 1.f : 0.f;
    }
    int co[K]; float mc[K];
#pragma unroll
    for (int c = 0; c < K; ++c) {
        const int ix = ix0 + c;
        const bool v = (ix >= 0) && (ix < WIN);
        co[c] = v ? ix : 0;
        mc[c] = v ? 1.f : 0.f;
    }

    float acc[NPY][16];
#pragma unroll
    for (int py = 0; py < NPY; ++py)
#pragma unroll
        for (int j = 0; j < 16; ++j) acc[py][j] = 0.f;

    for (int ic0 = 0; ic0 < CIN; ic0 += ICC) {
        __syncthreads();
        for (int t = tid; t < ICC * K2 * 16; t += 256) {
            int oc_l = t & 15, r = t >> 4, k = r % K2, ic_l = r / K2;
            sw[(ic_l * K2 + k) * 16 + oc_l] =
                w[((size_t)(oc0 + oc_l) * CIN + ic0 + ic_l) * K2 + k];
        }
        __syncthreads();
#pragma unroll 1
        for (int ic_l = 0; ic_l < ICC; ++ic_l) {
            const float* ip = in + (size_t)(n * CIN + ic0 + ic_l) * HIN * WIN;
            float patch[NR][K];
#pragma unroll
            for (int r = 0; r < NR; ++r)
#pragma unroll
                for (int c = 0; c < K; ++c)
                    patch[r][c] = ip[ro[r] + co[c]] * (mr[r] * mc[c]);
            const float* swp = &sw[ic_l * K2 * 16];
#pragma unroll
            for (int ky = 0; ky < K; ++ky) {
#pragma unroll
                for (int kx = 0; kx < K; ++kx) {
                    const float4* wp = (const float4*)&swp[(ky * K + kx) * 16];
                    float4 w0 = wp[0], w1 = wp[1], w2 = wp[2], w3 = wp[3];
#pragma unroll
                    for (int py = 0; py < NPY; ++py) {
                        const float v = patch[py * S + ky][kx];
                        acc[py][0]  = fmaf(w0.x, v, acc[py][0]);
                        acc[py][1]  = fmaf(w0.y, v, acc[py][1]);
                        acc[py][2]  = fmaf(w0.z, v, acc[py][2]);
                        acc[py][3]  = fmaf(w0.w, v, acc[py][3]);
                        acc[py][4]  = fmaf(w1.x, v, acc[py][4]);
                        acc[py][5]  = fmaf(w1.y, v, acc[py][5]);
                        acc[py][6]  = fmaf(w1.z, v, acc[py][6]);
                        acc[py][7]  = fmaf(w1.w, v, acc[py][7]);
                        acc[py][8]  = fmaf(w2.x, v, acc[py][8]);
                        acc[py][9]  = fmaf(w2.y, v, acc[py][9]);
                        acc[py][10] = fmaf(w2.z, v, acc[py][10]);
                        acc[py][11] = fmaf(w2.w, v, acc[py][11]);
                        acc[py][12] = fmaf(w3.x, v, acc[py][12]);
                        acc[py][13] = fmaf(w3.y, v, acc[py][13]);
                        acc[py][14] = fmaf(w3.z, v, acc[py][14]);
                        acc[py][15] = fmaf(w3.w, v, acc[py][15]);
                    }
                }
            }
        }
    }
#pragma unroll
    for (int py = 0; py < NPY; ++py) {
#pragma unroll
        for (int j = 0; j < 16; ++j) {
            float r = acc[py][j];
            if (BIAS) r += bias[oc0 + j];
            r = actf<ACT>(r);
            out[((size_t)(n * COUT + oc0 + j) * HOUT + oy0 + py) * WOUT + ox] = r;
        }
    }
}

// ---------------------------------------------------------------------------
// 3x3 pad1 stride1 conv on 64x64, NPY=4, scalar-path weights (block-uniform
// address -> s_load, no LDS, no barriers). Same arithmetic as conv_k.
// ---------------------------------------------------------------------------
template<int CIN, int ACT, bool BIAS>
__launch_bounds__(256, 2)
__global__ void conv3d_k(const float* __restrict__ in, const float* __restrict__ w,
                         const float* __restrict__ bias, float* __restrict__ out)
{
    constexpr int H = 64, W = 64, COUT = 128, NPY = 4, NR = NPY + 2;
    const int tid = threadIdx.x;
    const int tx = tid & 15, ty = tid >> 4;
    const int bx = blockIdx.x & 3, by = blockIdx.x >> 2;
    const int ox = bx * 16 + tx;
    const int oy0 = by * 64 + ty * NPY;
    const int oc0 = blockIdx.y * 16;
    const int n = blockIdx.z;
    const int ix0 = ox - 1, iy0 = oy0 - 1;

    int ro[NR]; float mr[NR];
#pragma unroll
    for (int r = 0; r < NR; ++r) {
        const int iy = iy0 + r;
        const bool v = (iy >= 0) && (iy < H);
        ro[r] = v ? iy * W : 0;
        mr[r] = v ? 1.f : 0.f;
    }
    int co[3]; float mc[3];
#pragma unroll
    for (int c = 0; c < 3; ++c) {
        const int ix = ix0 + c;
        const bool v = (ix >= 0) && (ix < W);
        co[c] = v ? ix : 0;
        mc[c] = v ? 1.f : 0.f;
    }

    float acc[NPY][16];
#pragma unroll
    for (int py = 0; py < NPY; ++py)
#pragma unroll
        for (int j = 0; j < 16; ++j) acc[py][j] = 0.f;

#pragma unroll 1
    for (int ic = 0; ic < CIN; ++ic) {
        const float* ip = in + (size_t)(n * CIN + ic) * H * W;
        float patch[NR][3];
#pragma unroll
        for (int r = 0; r < NR; ++r)
#pragma unroll
            for (int c = 0; c < 3; ++c)
                patch[r][c] = ip[ro[r] + co[c]] * (mr[r] * mc[c]);
#pragma unroll
        for (int ky = 0; ky < 3; ++ky) {
#pragma unroll
            for (int kx = 0; kx < 3; ++kx) {
                const int kk = ky * 3 + kx;
                float wv[16];
#pragma unroll
                for (int j = 0; j < 16; ++j)   // block-uniform -> s_load
                    wv[j] = w[((size_t)(oc0 + j) * CIN + ic) * 9 + kk];
#pragma unroll
                for (int py = 0; py < NPY; ++py) {
                    const float v = patch[py + ky][kx];
#pragma unroll
                    for (int j = 0; j < 16; ++j)
                        acc[py][j] = fmaf(wv[j], v, acc[py][j]);
                }
            }
        }
    }
#pragma unroll
    for (int py = 0; py < NPY; ++py) {
#pragma unroll
        for (int j = 0; j < 16; ++j) {
            float r = acc[py][j];
            if (BIAS) r += bias[oc0 + j];
            r = actf<ACT>(r);
            out[((size_t)(n * COUT + oc0 + j) * H + oy0 + py) * W + ox] = r;
        }
    }
}

// ---------------------------------------------------------------------------
// 1x1 conv over 64x64 maps, NPX pixels/thread, scalar-path weights (no LDS).
// ---------------------------------------------------------------------------
template<int CIN, int COUT, int NPX, int ACT, bool BIAS, bool INL, bool RESID, bool TOK>
__launch_bounds__(256, 3)
__global__ void conv1x1_k(const float* __restrict__ in, const float* __restrict__ w,
                          const float* __restrict__ bias, const float* __restrict__ resid,
                          float* __restrict__ out)
{
    constexpr int HW = 4096;
    const int tid = threadIdx.x;
    const int base = blockIdx.x * (256 * NPX) + tid;
    const int oc0 = blockIdx.y * 16;
    const int n = blockIdx.z;

    float acc[NPX][16];
#pragma unroll
    for (int p = 0; p < NPX; ++p)
#pragma unroll
        for (int j = 0; j < 16; ++j) acc[p][j] = 0.f;

    const float* ip = in + (size_t)n * CIN * HW;
#pragma unroll 2
    for (int ic = 0; ic < CIN; ++ic) {
        float v[NPX];
#pragma unroll
        for (int p = 0; p < NPX; ++p) {
            float t = ip[(size_t)ic * HW + base + 256 * p];
            if (INL) t = lrelu_in(t);
            v[p] = t;
        }
        float wv[16];
#pragma unroll
        for (int j = 0; j < 16; ++j)           // block-uniform -> s_load
            wv[j] = w[(size_t)(oc0 + j) * CIN + ic];
#pragma unroll
        for (int j = 0; j < 16; ++j)
#pragma unroll
            for (int p = 0; p < NPX; ++p)
                acc[p][j] = fmaf(wv[j], v[p], acc[p][j]);
    }
#pragma unroll
    for (int p = 0; p < NPX; ++p) {
        const int pix = base + 256 * p;
#pragma unroll
        for (int j = 0; j < 16; ++j) {
            float r = acc[p][j];
            if (BIAS) r += bias[oc0 + j];
            r = actf<ACT>(r);
            if (RESID) r += resid[((size_t)(n * COUT + oc0 + j)) * HW + pix];
            if (TOK)
                out[((size_t)n * HW + pix) * COUT + oc0 + j] = r;
            else
                out[((size_t)(n * COUT + oc0 + j)) * HW + pix] = r;
        }
    }
}

// ---------------------------------------------------------------------------
// ConvTranspose2d k=4 s=2 p=1, parity decomposition. (validated R2/R5/R8)
// ---------------------------------------------------------------------------
template<int CIN, int COUT, int OCT, int HIN, int ICC, int ACT, bool INL>
__launch_bounds__(256, 3)
__global__ void convt_k(const float* __restrict__ in, const float* __restrict__ w,
                        const float* __restrict__ bias, float* __restrict__ out)
{
    constexpr int WIN = HIN, HOUT = 2 * HIN, WOUT = 2 * HIN;
    __shared__ float sw[ICC * 16 * OCT];
    const int tid = threadIdx.x;
    const int tx = tid & 15, ty = tid >> 4;
    constexpr int TBW = WOUT / 32;
    const int bx = blockIdx.x % TBW, by = blockIdx.x / TBW;
    const int A = by * 16 + ty;
    const int C = bx * 16 + tx;
    const int oc0 = blockIdx.y * OCT;
    const int n = blockIdx.z;

    int offs[9]; float msk[9];
#pragma unroll
    for (int dy = 0; dy < 3; ++dy) {
#pragma unroll
        for (int dx = 0; dx < 3; ++dx) {
            const int iy = A - 1 + dy, ix = C - 1 + dx;
            const bool v = (iy >= 0) && (iy < HIN) && (ix >= 0) && (ix < WIN);
            offs[dy * 3 + dx] = v ? iy * WIN + ix : 0;
            msk[dy * 3 + dx] = v ? 1.f : 0.f;
        }
    }

    float acc[4 * OCT];
#pragma unroll
    for (int j = 0; j < 4 * OCT; ++j) acc[j] = 0.f;

    for (int ic0 = 0; ic0 < CIN; ic0 += ICC) {
        __syncthreads();
        for (int t = tid; t < ICC * 16 * OCT; t += 256) {
            int oc_l = t % OCT, r = t / OCT, k = r & 15, ic_l = r >> 4;
            sw[(ic_l * 16 + k) * OCT + oc_l] =
                w[((size_t)(ic0 + ic_l) * COUT + oc0 + oc_l) * 16 + k];
        }
        __syncthreads();
#pragma unroll 1
        for (int ic_l = 0; ic_l < ICC; ++ic_l) {
            const float* ip = in + (size_t)(n * CIN + ic0 + ic_l) * HIN * WIN;
            float in9[9];
#pragma unroll
            for (int j = 0; j < 9; ++j) {
                float v = ip[offs[j]] * msk[j];
                if (INL) v = lrelu_in(v);
                in9[j] = v;
            }
#pragma unroll
            for (int ky = 0; ky < 4; ++ky) {
                const int ry = (ky + 1) & 1;
                const int dy = 2 - ((ky + 1) >> 1);
#pragma unroll
                for (int kx = 0; kx < 4; ++kx) {
                    const int rx = (kx + 1) & 1;
                    const int dx = 2 - ((kx + 1) >> 1);
                    const float v = in9[dy * 3 + dx];
                    const int po = ry * 2 + rx;
                    const float4* wp = (const float4*)&sw[(ic_l * 16 + ky * 4 + kx) * OCT];
#pragma unroll
                    for (int q4 = 0; q4 < OCT / 4; ++q4) {
                        float4 wv = wp[q4];
                        acc[po * OCT + q4 * 4 + 0] = fmaf(wv.x, v, acc[po * OCT + q4 * 4 + 0]);
                        acc[po * OCT + q4 * 4 + 1] = fmaf(wv.y, v, acc[po * OCT + q4 * 4 + 1]);
                        acc[po * OCT + q4 * 4 + 2] = fmaf(wv.z, v, acc[po * OCT + q4 * 4 + 2]);
                        acc[po * OCT + q4 * 4 + 3] = fmaf(wv.w, v, acc[po * OCT + q4 * 4 + 3]);
                    }
                }
            }
        }
    }
#pragma unroll
    for (int po = 0; po < 4; ++po) {
        const int ry = po >> 1, rx = po & 1;
        const int oy = 2 * A + ry, ox = 2 * C + rx;
#pragma unroll
        for (int j = 0; j < OCT; ++j) {
            float r = acc[po * OCT + j] + bias[oc0 + j];
            r = actf<ACT>(r);
            out[((size_t)(n * COUT + oc0 + j) * HOUT + oy) * WOUT + ox] = r;
        }
    }
}

// ---------------------------------------------------------------------------
// Codebook norms, precomputed once. (validated R7/R8/R10)
// ---------------------------------------------------------------------------
__global__ void norm_k(const float* __restrict__ cb, float* __restrict__ nrm) {
    const int c = blockIdx.x * 256 + threadIdx.x;   // 0..2047
    const float4* p = (const float4*)(cb + (size_t)c * 64);
    float a0 = 0.f, a1 = 0.f, a2 = 0.f, a3 = 0.f;
#pragma unroll
    for (int i = 0; i < 16; ++i) {
        float4 v = p[i];
        a0 = fmaf(v.x, v.x, a0); a1 = fmaf(v.y, v.y, a1);
        a2 = fmaf(v.z, v.z, a2); a3 = fmaf(v.w, v.w, a3);
    }
    nrm[c] = (a0 + a1) + (a2 + a3);
}

// ---------------------------------------------------------------------------
// Residual VQ v3: 1 thread = 1 token (R2 full-lane layout), codebook read
// via wave-uniform global loads (scalar path), NO LDS. Distance/update
// arithmetic verbatim from validated kernels; strict < first-min.
// ---------------------------------------------------------------------------
__launch_bounds__(256)
__global__ void rvq3_k(const float* __restrict__ z, const float* __restrict__ cb,
                       const float* __restrict__ nrm,
                       float* __restrict__ q, float* __restrict__ idx_out,
                       float* __restrict__ loss_acc)
{
    const int tid = threadIdx.x;
    const int t = blockIdx.x * 256 + tid;

    float r[64];
    {
        const float4* zp = (const float4*)(z + (size_t)t * 64);
#pragma unroll
        for (int i = 0; i < 16; ++i) {
            float4 v = zp[i];
            r[4 * i + 0] = v.x; r[4 * i + 1] = v.y;
            r[4 * i + 2] = v.z; r[4 * i + 3] = v.w;
        }
    }

    for (int s = 0; s < 4; ++s) {
        float s0 = 0.f, s1 = 0.f, s2 = 0.f, s3 = 0.f;
#pragma unroll
        for (int i = 0; i < 64; i += 4) {
            s0 = fmaf(r[i + 0], r[i + 0], s0);
            s1 = fmaf(r[i + 1], r[i + 1], s1);
            s2 = fmaf(r[i + 2], r[i + 2], s2);
            s3 = fmaf(r[i + 3], r[i + 3], s3);
        }
        const float sr2 = (s0 + s1) + (s2 + s3);

        float dmin = 3.4e38f;
        int best = 0;
        const float* cbs_ = cb + (size_t)s * 512 * 64;
        const float* nr_ = nrm + s * 512;
#pragma unroll 2
        for (int kk = 0; kk < 512; ++kk) {
            const float4* cp = (const float4*)(cbs_ + (size_t)kk * 64); // uniform -> s_load
            float d0 = 0.f, d1 = 0.f, d2 = 0.f, d3 = 0.f;
#pragma unroll
            for (int i = 0; i < 16; ++i) {
                const float4 c = cp[i];
                d0 = fmaf(r[4 * i + 0], c.x, d0);
                d1 = fmaf(r[4 * i + 1], c.y, d1);
                d2 = fmaf(r[4 * i + 2], c.z, d2);
                d3 = fmaf(r[4 * i + 3], c.w, d3);
            }
            const float dot = (d0 + d1) + (d2 + d3);
            const float d = fmaf(-2.f, dot, sr2) + nr_[kk];
            if (d < dmin) { dmin = d; best = kk; }
        }

        float lv = dmin;
#pragma unroll
        for (int off = 32; off; off >>= 1) lv += __shfl_down(lv, off, 64);
        if ((tid & 63) == 0) atomicAdd(&loss_acc[s], lv);

        idx_out[(size_t)t * 4 + s] = (float)best;

        const float4* cbest = (const float4*)(cbs_ + (size_t)best * 64);
#pragma unroll
        for (int i = 0; i < 16; ++i) {
            const float4 c = cbest[i];
            r[4 * i + 0] -= c.x; r[4 * i + 1] -= c.y;
            r[4 * i + 2] -= c.z; r[4 * i + 3] -= c.w;
        }
    }
    // q = z - r_final, NCHW
    {
        const int n = t >> 12, pix = t & 4095;
        float* qp = q + (size_t)n * 64 * 4096 + pix;
        const float4* zp = (const float4*)(z + (size_t)t * 64);
#pragma unroll
        for (int i = 0; i < 16; ++i) {
            const float4 v = zp[i];
            qp[(size_t)(4 * i + 0) * 4096] = v.x - r[4 * i + 0];
            qp[(size_t)(4 * i + 1) * 4096] = v.y - r[4 * i + 1];
            qp[(size_t)(4 * i + 2) * 4096] = v.z - r[4 * i + 2];
            qp[(size_t)(4 * i + 3) * 4096] = v.w - r[4 * i + 3];
        }
    }
}

__global__ void init_k(float* loss_acc) {
    if (threadIdx.x < 4) loss_acc[threadIdx.x] = 0.f;
}
__global__ void fin_k(const float* __restrict__ loss_acc, float* __restrict__ out_loss) {
    if (threadIdx.x < 4)
        out_loss[threadIdx.x] = loss_acc[threadIdx.x] * (0.25f / 4194304.f); // BETA/(N*D)
}

// ---------------------------------------------------------------------------
extern "C" void kernel_launch(void* const* d_in, const int* in_sizes, int n_in,
                              void* d_out, int out_size, void* d_ws, size_t ws_size,
                              hipStream_t stream)
{
    const float* x    = (const float*)d_in[0];
    const float* e1w  = (const float*)d_in[1];  const float* e1b = (const float*)d_in[2];
    const float* e2w  = (const float*)d_in[3];  const float* e2b = (const float*)d_in[4];
    const float* e3w  = (const float*)d_in[5];  const float* e3b = (const float*)d_in[6];
    const float* r1aw = (const float*)d_in[7];  const float* r1bw = (const float*)d_in[8];
    const float* r2aw = (const float*)d_in[9];  const float* r2bw = (const float*)d_in[10];
    const float* e4w  = (const float*)d_in[11]; const float* e4b = (const float*)d_in[12];
    const float* cbs  = (const float*)d_in[13];
    const float* d1w  = (const float*)d_in[14]; const float* d1b = (const float*)d_in[15];
    const float* dr1aw= (const float*)d_in[16]; const float* dr1bw = (const float*)d_in[17];
    const float* dr2aw= (const float*)d_in[18]; const float* dr2bw = (const float*)d_in[19];
    const float* dt1w = (const float*)d_in[20]; const float* dt1b = (const float*)d_in[21];
    const float* dt2w = (const float*)d_in[22]; const float* dt2b = (const float*)d_in[23];

    float* out = (float*)d_out;
    float* ws  = (float*)d_ws;

    float* BIG = ws;                    // 16.78M floats (e1 out / dt1 out)
    float* P2  = BIG;
    float* P3  = BIG + 8388608;
    float* P1  = ws + 16777216;
    float* Z   = ws + 25165824;
    float* Q   = ws + 29360128;
    float* LACC= ws + 33554432;         // 4 floats
    float* NRM = ws + 33554448;         // 2048 floats

    float* out_recons = out;                    // 16*4*256*256 = 4194304
    float* out_idx    = out + 4194304;          // 16*64*64*4   = 262144
    float* out_loss   = out + 4194304 + 262144; // 4

    init_k<<<1, 64, 0, stream>>>(LACC);
    norm_k<<<8, 256, 0, stream>>>(cbs, NRM);

    // ---- encoder ----
    conv_k<4, 64, 4, 2, 1, 256, 256, 128, 128, 4, 1, 2, true>
        <<<dim3(64, 4, 16), 256, 0, stream>>>(x, e1w, e1b, BIG);
    conv_k<64, 128, 4, 2, 1, 128, 128, 64, 64, 16, 2, 2, true>
        <<<dim3(8, 8, 16), 256, 0, stream>>>(BIG, e2w, e2b, P1);
    conv3d_k<128, 2, true>
        <<<dim3(4, 8, 16), 256, 0, stream>>>(P1, e3w, e3b, P2);
    conv3d_k<128, 1, false>
        <<<dim3(4, 8, 16), 256, 0, stream>>>(P2, r1aw, nullptr, P3);
    conv1x1_k<128, 128, 4, 0, false, false, true, false>
        <<<dim3(4, 8, 16), 256, 0, stream>>>(P3, r1bw, nullptr, P2, P1);
    conv3d_k<128, 1, false>
        <<<dim3(4, 8, 16), 256, 0, stream>>>(P1, r2aw, nullptr, P3);
    conv1x1_k<128, 128, 4, 0, false, false, true, false>
        <<<dim3(4, 8, 16), 256, 0, stream>>>(P3, r2bw, nullptr, P1, P2);
    conv1x1_k<128, 64, 2, 2, true, true, false, true>
        <<<dim3(8, 4, 16), 256, 0, stream>>>(P2, e4w, e4b, nullptr, Z);

    // ---- residual VQ ----
    rvq3_k<<<256, 256, 0, stream>>>(Z, cbs, NRM, Q, out_idx, LACC);
    fin_k<<<1, 64, 0, stream>>>(LACC, out_loss);

    // ---- decoder ----
    conv3d_k<64, 2, true>
        <<<dim3(4, 8, 16), 256, 0, stream>>>(Q, d1w, d1b, P1);
    conv3d_k<128, 1, false>
        <<<dim3(4, 8, 16), 256, 0, stream>>>(P1, dr1aw, nullptr, P2);
    conv1x1_k<128, 128, 4, 0, false, false, true, false>
        <<<dim3(4, 8, 16), 256, 0, stream>>>(P2, dr1bw, nullptr, P1, P3);
    conv3d_k<128, 1, false>
        <<<dim3(4, 8, 16), 256, 0, stream>>>(P3, dr2aw, nullptr, P2);
    conv1x1_k<128, 128, 4, 0, false, false, true, false>
        <<<dim3(4, 8, 16), 256, 0, stream>>>(P2, dr2bw, nullptr, P3, P1);
    convt_k<128, 64, 16, 64, 8, 2, true>
        <<<dim3(16, 4, 16), 256, 0, stream>>>(P1, dt1w, dt1b, BIG);
    convt_k<64, 4, 4, 128, 16, 1, false>
        <<<dim3(64, 1, 16), 256, 0, stream>>>(BIG, dt2w, dt2b, out_recons);
}

// Round 12
// 2912.826 us; speedup vs baseline: 1.3209x; 1.3209x over previous
//
#include <hip/hip_runtime.h>
#include <cstddef>

// ---------------------------------------------------------------------------
// RQ-VAE forward on MI355X. Round 12: revert to R8 best (2858us) + e2 NPY=4.
// R11 post-mortem: "uniform->s_load" theory failed (compiler kept per-wave
// vector loads; rvq3 FETCH 18GB, 1000us; scalar-weight convs -500us too).
// Keep LDS staging everywhere (validated). One change vs R8: e2 NPY 2->4
// (same transformation that won on the 3x3 convs in R8).
// ---------------------------------------------------------------------------

template<int ACT> __device__ __forceinline__ float actf(float v) {
    if constexpr (ACT == 1) return v > 0.f ? v : 0.f;            // relu
    else if constexpr (ACT == 2) return v > 0.f ? v : 0.01f * v; // leaky relu
    else return v;
}
__device__ __forceinline__ float lrelu_in(float v) { return v > 0.f ? v : 0.01f * v; }

// ---------------------------------------------------------------------------
// Direct conv: thread = NPY vertical output pixels x 16 output channels.
// (validated R8)
// ---------------------------------------------------------------------------
template<int CIN, int COUT, int K, int S, int P, int HIN, int WIN, int HOUT, int WOUT,
         int ICC, int NPY, int ACT, bool BIAS>
__launch_bounds__(256, (NPY >= 4 ? 2 : 4))
__global__ void conv_k(const float* __restrict__ in, const float* __restrict__ w,
                       const float* __restrict__ bias, float* __restrict__ out)
{
    constexpr int K2 = K * K;
    constexpr int NR = S * (NPY - 1) + K;
    constexpr int BH = 16 * NPY;
    __shared__ float sw[ICC * K2 * 16];
    const int tid = threadIdx.x;
    const int tx = tid & 15, ty = tid >> 4;
    constexpr int TW = WOUT / 16;
    const int bx = blockIdx.x % TW, by = blockIdx.x / TW;
    const int ox = bx * 16 + tx;
    const int oy0 = by * BH + ty * NPY;
    const int oc0 = blockIdx.y * 16;
    const int n = blockIdx.z;
    const int ix0 = ox * S - P, iy0 = oy0 * S - P;

    int ro[NR]; float mr[NR];
#pragma unroll
    for (int r = 0; r < NR; ++r) {
        const int iy = iy0 + r;
        const bool v = (iy >= 0) && (iy < HIN);
        ro[r] = v ? iy * WIN : 0;
        mr[r] = v ? 1.f : 0.f;
    }
    int co[K]; float mc[K];
#pragma unroll
    for (int c = 0; c < K; ++c) {
        const int ix = ix0 + c;
        const bool v = (ix >= 0) && (ix < WIN);
        co[c] = v ? ix : 0;
        mc[c] = v ? 1.f : 0.f;
    }

    float acc[NPY][16];
#pragma unroll
    for (int py = 0; py < NPY; ++py)
#pragma unroll
        for (int j = 0; j < 16; ++j) acc[py][j] = 0.f;

    for (int ic0 = 0; ic0 < CIN; ic0 += ICC) {
        __syncthreads();
        for (int t = tid; t < ICC * K2 * 16; t += 256) {
            int oc_l = t & 15, r = t >> 4, k = r % K2, ic_l = r / K2;
            sw[(ic_l * K2 + k) * 16 + oc_l] =
                w[((size_t)(oc0 + oc_l) * CIN + ic0 + ic_l) * K2 + k];
        }
        __syncthreads();
#pragma unroll 1
        for (int ic_l = 0; ic_l < ICC; ++ic_l) {
            const float* ip = in + (size_t)(n * CIN + ic0 + ic_l) * HIN * WIN;
            float patch[NR][K];
#pragma unroll
            for (int r = 0; r < NR; ++r)
#pragma unroll
                for (int c = 0; c < K; ++c)
                    patch[r][c] = ip[ro[r] + co[c]] * (mr[r] * mc[c]);
            const float* swp = &sw[ic_l * K2 * 16];
#pragma unroll
            for (int ky = 0; ky < K; ++ky) {
#pragma unroll
                for (int kx = 0; kx < K; ++kx) {
                    const float4* wp = (const float4*)&swp[(ky * K + kx) * 16];
                    float4 w0 = wp[0], w1 = wp[1], w2 = wp[2], w3 = wp[3];
#pragma unroll
                    for (int py = 0; py < NPY; ++py) {
                        const float v = patch[py * S + ky][kx];
                        acc[py][0]  = fmaf(w0.x, v, acc[py][0]);
                        acc[py][1]  = fmaf(w0.y, v, acc[py][1]);
                        acc[py][2]  = fmaf(w0.z, v, acc[py][2]);
                        acc[py][3]  = fmaf(w0.w, v, acc[py][3]);
                        acc[py][4]  = fmaf(w1.x, v, acc[py][4]);
                        acc[py][5]  = fmaf(w1.y, v, acc[py][5]);
                        acc[py][6]  = fmaf(w1.z, v, acc[py][6]);
                        acc[py][7]  = fmaf(w1.w, v, acc[py][7]);
                        acc[py][8]  = fmaf(w2.x, v, acc[py][8]);
                        acc[py][9]  = fmaf(w2.y, v, acc[py][9]);
                        acc[py][10] = fmaf(w2.z, v, acc[py][10]);
                        acc[py][11] = fmaf(w2.w, v, acc[py][11]);
                        acc[py][12] = fmaf(w3.x, v, acc[py][12]);
                        acc[py][13] = fmaf(w3.y, v, acc[py][13]);
                        acc[py][14] = fmaf(w3.z, v, acc[py][14]);
                        acc[py][15] = fmaf(w3.w, v, acc[py][15]);
                    }
                }
            }
        }
    }
#pragma unroll
    for (int py = 0; py < NPY; ++py) {
#pragma unroll
        for (int j = 0; j < 16; ++j) {
            float r = acc[py][j];
            if (BIAS) r += bias[oc0 + j];
            r = actf<ACT>(r);
            out[((size_t)(n * COUT + oc0 + j) * HOUT + oy0 + py) * WOUT + ox] = r;
        }
    }
}

// ---------------------------------------------------------------------------
// 1x1 conv over 64x64 maps (HW=4096), NPX pixels per thread. (validated R8)
// ---------------------------------------------------------------------------
template<int CIN, int COUT, int NPX, int ACT, bool BIAS, bool INL, bool RESID, bool TOK>
__launch_bounds__(256, 3)
__global__ void conv1x1_k(const float* __restrict__ in, const float* __restrict__ w,
                          const float* __restrict__ bias, const float* __restrict__ resid,
                          float* __restrict__ out)
{
    constexpr int HW = 4096;
    __shared__ float sw[16 * CIN];
    const int tid = threadIdx.x;
    const int base = blockIdx.x * (256 * NPX) + tid;
    const int oc0 = blockIdx.y * 16;
    const int n = blockIdx.z;

    for (int t = tid; t < 16 * CIN; t += 256) {
        int oc_l = t & 15, ic = t >> 4;
        sw[ic * 16 + oc_l] = w[(size_t)(oc0 + oc_l) * CIN + ic];
    }
    __syncthreads();

    float acc[NPX][16];
#pragma unroll
    for (int p = 0; p < NPX; ++p)
#pragma unroll
        for (int j = 0; j < 16; ++j) acc[p][j] = 0.f;

    const float* ip = in + (size_t)n * CIN * HW;
#pragma unroll 2
    for (int ic = 0; ic < CIN; ++ic) {
        float v[NPX];
#pragma unroll
        for (int p = 0; p < NPX; ++p) {
            float t = ip[(size_t)ic * HW + base + 256 * p];
            if (INL) t = lrelu_in(t);
            v[p] = t;
        }
        const float4* wp = (const float4*)&sw[ic * 16];
#pragma unroll
        for (int q4 = 0; q4 < 4; ++q4) {
            const float4 wv = wp[q4];
#pragma unroll
            for (int p = 0; p < NPX; ++p) {
                acc[p][q4 * 4 + 0] = fmaf(wv.x, v[p], acc[p][q4 * 4 + 0]);
                acc[p][q4 * 4 + 1] = fmaf(wv.y, v[p], acc[p][q4 * 4 + 1]);
                acc[p][q4 * 4 + 2] = fmaf(wv.z, v[p], acc[p][q4 * 4 + 2]);
                acc[p][q4 * 4 + 3] = fmaf(wv.w, v[p], acc[p][q4 * 4 + 3]);
            }
        }
    }
#pragma unroll
    for (int p = 0; p < NPX; ++p) {
        const int pix = base + 256 * p;
#pragma unroll
        for (int j = 0; j < 16; ++j) {
            float r = acc[p][j];
            if (BIAS) r += bias[oc0 + j];
            r = actf<ACT>(r);
            if (RESID) r += resid[((size_t)(n * COUT + oc0 + j)) * HW + pix];
            if (TOK)
                out[((size_t)n * HW + pix) * COUT + oc0 + j] = r;
            else
                out[((size_t)(n * COUT + oc0 + j)) * HW + pix] = r;
        }
    }
}

// ---------------------------------------------------------------------------
// ConvTranspose2d k=4 s=2 p=1, parity decomposition. (validated R2/R5/R8)
// ---------------------------------------------------------------------------
template<int CIN, int COUT, int OCT, int HIN, int ICC, int ACT, bool INL>
__launch_bounds__(256, 3)
__global__ void convt_k(const float* __restrict__ in, const float* __restrict__ w,
                        const float* __restrict__ bias, float* __restrict__ out)
{
    constexpr int WIN = HIN, HOUT = 2 * HIN, WOUT = 2 * HIN;
    __shared__ float sw[ICC * 16 * OCT];
    const int tid = threadIdx.x;
    const int tx = tid & 15, ty = tid >> 4;
    constexpr int TBW = WOUT / 32;
    const int bx = blockIdx.x % TBW, by = blockIdx.x / TBW;
    const int A = by * 16 + ty;
    const int C = bx * 16 + tx;
    const int oc0 = blockIdx.y * OCT;
    const int n = blockIdx.z;

    int offs[9]; float msk[9];
#pragma unroll
    for (int dy = 0; dy < 3; ++dy) {
#pragma unroll
        for (int dx = 0; dx < 3; ++dx) {
            const int iy = A - 1 + dy, ix = C - 1 + dx;
            const bool v = (iy >= 0) && (iy < HIN) && (ix >= 0) && (ix < WIN);
            offs[dy * 3 + dx] = v ? iy * WIN + ix : 0;
            msk[dy * 3 + dx] = v ? 1.f : 0.f;
        }
    }

    float acc[4 * OCT];
#pragma unroll
    for (int j = 0; j < 4 * OCT; ++j) acc[j] = 0.f;

    for (int ic0 = 0; ic0 < CIN; ic0 += ICC) {
        __syncthreads();
        for (int t = tid; t < ICC * 16 * OCT; t += 256) {
            int oc_l = t % OCT, r = t / OCT, k = r & 15, ic_l = r >> 4;
            sw[(ic_l * 16 + k) * OCT + oc_l] =
                w[((size_t)(ic0 + ic_l) * COUT + oc0 + oc_l) * 16 + k];
        }
        __syncthreads();
#pragma unroll 1
        for (int ic_l = 0; ic_l < ICC; ++ic_l) {
            const float* ip = in + (size_t)(n * CIN + ic0 + ic_l) * HIN * WIN;
            float in9[9];
#pragma unroll
            for (int j = 0; j < 9; ++j) {
                float v = ip[offs[j]] * msk[j];
                if (INL) v = lrelu_in(v);
                in9[j] = v;
            }
#pragma unroll
            for (int ky = 0; ky < 4; ++ky) {
                const int ry = (ky + 1) & 1;
                const int dy = 2 - ((ky + 1) >> 1);
#pragma unroll
                for (int kx = 0; kx < 4; ++kx) {
                    const int rx = (kx + 1) & 1;
                    const int dx = 2 - ((kx + 1) >> 1);
                    const float v = in9[dy * 3 + dx];
                    const int po = ry * 2 + rx;
                    const float4* wp = (const float4*)&sw[(ic_l * 16 + ky * 4 + kx) * OCT];
#pragma unroll
                    for (int q4 = 0; q4 < OCT / 4; ++q4) {
                        float4 wv = wp[q4];
                        acc[po * OCT + q4 * 4 + 0] = fmaf(wv.x, v, acc[po * OCT + q4 * 4 + 0]);
                        acc[po * OCT + q4 * 4 + 1] = fmaf(wv.y, v, acc[po * OCT + q4 * 4 + 1]);
                        acc[po * OCT + q4 * 4 + 2] = fmaf(wv.z, v, acc[po * OCT + q4 * 4 + 2]);
                        acc[po * OCT + q4 * 4 + 3] = fmaf(wv.w, v, acc[po * OCT + q4 * 4 + 3]);
                    }
                }
            }
        }
    }
#pragma unroll
    for (int po = 0; po < 4; ++po) {
        const int ry = po >> 1, rx = po & 1;
        const int oy = 2 * A + ry, ox = 2 * C + rx;
#pragma unroll
        for (int j = 0; j < OCT; ++j) {
            float r = acc[po * OCT + j] + bias[oc0 + j];
            r = actf<ACT>(r);
            out[((size_t)(n * COUT + oc0 + j) * HOUT + oy) * WOUT + ox] = r;
        }
    }
}

// ---------------------------------------------------------------------------
// Codebook norms, precomputed once. (validated R7/R8/R10)
// ---------------------------------------------------------------------------
__global__ void norm_k(const float* __restrict__ cb, float* __restrict__ nrm) {
    const int c = blockIdx.x * 256 + threadIdx.x;   // 0..2047
    const float4* p = (const float4*)(cb + (size_t)c * 64);
    float a0 = 0.f, a1 = 0.f, a2 = 0.f, a3 = 0.f;
#pragma unroll
    for (int i = 0; i < 16; ++i) {
        float4 v = p[i];
        a0 = fmaf(v.x, v.x, a0); a1 = fmaf(v.y, v.y, a1);
        a2 = fmaf(v.z, v.z, a2); a3 = fmaf(v.w, v.w, a3);
    }
    nrm[c] = (a0 + a1) + (a2 + a3);
}

// ---------------------------------------------------------------------------
// Residual VQ: 2 lanes/token, block=128, grid=1024 + norm table. (validated
// R7/R8: ~540us, LDS-issue-bound plateau for this layout.)
// ---------------------------------------------------------------------------
__launch_bounds__(128)
__global__ void rvq_k(const float* __restrict__ z, const float* __restrict__ cb,
                      const float* __restrict__ nrm,
                      float* __restrict__ q, float* __restrict__ idx_out,
                      float* __restrict__ loss_acc)
{
    __shared__ float scb[128 * 64];
    __shared__ float ssc[128];
    const int tid = threadIdx.x;
    const int h = tid & 1;
    const int tloc = tid >> 1;
    const int t = blockIdx.x * 64 + tloc;

    float zr[32], r[32];
    const float4* zp = (const float4*)(z + (size_t)t * 64 + h * 32);
#pragma unroll
    for (int i = 0; i < 8; ++i) {
        float4 v = zp[i];
        zr[4 * i + 0] = v.x; zr[4 * i + 1] = v.y; zr[4 * i + 2] = v.z; zr[4 * i + 3] = v.w;
        r[4 * i + 0] = v.x;  r[4 * i + 1] = v.y;  r[4 * i + 2] = v.z;  r[4 * i + 3] = v.w;
    }

    for (int s = 0; s < 4; ++s) {
        float s0 = 0.f, s1 = 0.f, s2 = 0.f, s3 = 0.f;
#pragma unroll
        for (int i = 0; i < 32; i += 4) {
            s0 = fmaf(r[i + 0], r[i + 0], s0);
            s1 = fmaf(r[i + 1], r[i + 1], s1);
            s2 = fmaf(r[i + 2], r[i + 2], s2);
            s3 = fmaf(r[i + 3], r[i + 3], s3);
        }
        float sr2 = (s0 + s1) + (s2 + s3);
        sr2 += __shfl_xor(sr2, 1, 64);

        float dmin = 3.4e38f;
        int best = 0;
        for (int pass = 0; pass < 4; ++pass) {
            __syncthreads();
            const float* src = cb + ((size_t)s * 512 + pass * 128) * 64;
            for (int i2 = tid; i2 < 128 * 64 / 4; i2 += 128)
                ((float4*)scb)[i2] = ((const float4*)src)[i2];
            ssc[tid] = nrm[(size_t)s * 512 + pass * 128 + tid];
            __syncthreads();
#pragma unroll 2
            for (int kk = 0; kk < 128; ++kk) {
                const float4* cp = (const float4*)&scb[kk * 64 + h * 32];
                float d0 = 0.f, d1 = 0.f, d2 = 0.f, d3 = 0.f;
#pragma unroll
                for (int i = 0; i < 8; ++i) {
                    float4 c = cp[i];
                    d0 = fmaf(r[4 * i + 0], c.x, d0);
                    d1 = fmaf(r[4 * i + 1], c.y, d1);
                    d2 = fmaf(r[4 * i + 2], c.z, d2);
                    d3 = fmaf(r[4 * i + 3], c.w, d3);
                }
                float dot = (d0 + d1) + (d2 + d3);
                dot += __shfl_xor(dot, 1, 64);
                const float d = fmaf(-2.f, dot, sr2) + ssc[kk];
                if (d < dmin) { dmin = d; best = pass * 128 + kk; }
            }
        }
        float lv = (h == 0) ? dmin : 0.f;
#pragma unroll
        for (int off = 32; off; off >>= 1) lv += __shfl_down(lv, off, 64);
        if ((tid & 63) == 0) atomicAdd(&loss_acc[s], lv);

        if (h == 0) idx_out[(size_t)t * 4 + s] = (float)best;

        const float4* cbest = (const float4*)(cb + ((size_t)s * 512 + best) * 64 + h * 32);
#pragma unroll
        for (int i = 0; i < 8; ++i) {
            float4 c = cbest[i];
            r[4 * i + 0] -= c.x; r[4 * i + 1] -= c.y;
            r[4 * i + 2] -= c.z; r[4 * i + 3] -= c.w;
        }
    }
    const int n = t >> 12, pix = t & 4095;
    float* qp = q + (size_t)n * 64 * 4096 + pix;
#pragma unroll
    for (int i = 0; i < 32; ++i)
        qp[(size_t)(h * 32 + i) * 4096] = zr[i] - r[i];
}

__global__ void init_k(float* loss_acc) {
    if (threadIdx.x < 4) loss_acc[threadIdx.x] = 0.f;
}
__global__ void fin_k(const float* __restrict__ loss_acc, float* __restrict__ out_loss) {
    if (threadIdx.x < 4)
        out_loss[threadIdx.x] = loss_acc[threadIdx.x] * (0.25f / 4194304.f); // BETA/(N*D)
}

// ---------------------------------------------------------------------------
extern "C" void kernel_launch(void* const* d_in, const int* in_sizes, int n_in,
                              void* d_out, int out_size, void* d_ws, size_t ws_size,
                              hipStream_t stream)
{
    const float* x    = (const float*)d_in[0];
    const float* e1w  = (const float*)d_in[1];  const float* e1b = (const float*)d_in[2];
    const float* e2w  = (const float*)d_in[3];  const float* e2b = (const float*)d_in[4];
    const float* e3w  = (const float*)d_in[5];  const float* e3b = (const float*)d_in[6];
    const float* r1aw = (const float*)d_in[7];  const float* r1bw = (const float*)d_in[8];
    const float* r2aw = (const float*)d_in[9];  const float* r2bw = (const float*)d_in[10];
    const float* e4w  = (const float*)d_in[11]; const float* e4b = (const float*)d_in[12];
    const float* cbs  = (const float*)d_in[13];
    const float* d1w  = (const float*)d_in[14]; const float* d1b = (const float*)d_in[15];
    const float* dr1aw= (const float*)d_in[16]; const float* dr1bw = (const float*)d_in[17];
    const float* dr2aw= (const float*)d_in[18]; const float* dr2bw = (const float*)d_in[19];
    const float* dt1w = (const float*)d_in[20]; const float* dt1b = (const float*)d_in[21];
    const float* dt2w = (const float*)d_in[22]; const float* dt2b = (const float*)d_in[23];

    float* out = (float*)d_out;
    float* ws  = (float*)d_ws;

    float* BIG = ws;                    // 16.78M floats (e1 out / dt1 out)
    float* P2  = BIG;
    float* P3  = BIG + 8388608;
    float* P1  = ws + 16777216;
    float* Z   = ws + 25165824;
    float* Q   = ws + 29360128;
    float* LACC= ws + 33554432;         // 4 floats
    float* NRM = ws + 33554448;         // 2048 floats

    float* out_recons = out;                    // 16*4*256*256 = 4194304
    float* out_idx    = out + 4194304;          // 16*64*64*4   = 262144
    float* out_loss   = out + 4194304 + 262144; // 4

    init_k<<<1, 64, 0, stream>>>(LACC);
    norm_k<<<8, 256, 0, stream>>>(cbs, NRM);

    // ---- encoder ----
    conv_k<4, 64, 4, 2, 1, 256, 256, 128, 128, 4, 1, 2, true>
        <<<dim3(64, 4, 16), 256, 0, stream>>>(x, e1w, e1b, BIG);
    conv_k<64, 128, 4, 2, 1, 128, 128, 64, 64, 16, 4, 2, true>
        <<<dim3(4, 8, 16), 256, 0, stream>>>(BIG, e2w, e2b, P1);
    conv_k<128, 128, 3, 1, 1, 64, 64, 64, 64, 16, 4, 2, true>
        <<<dim3(4, 8, 16), 256, 0, stream>>>(P1, e3w, e3b, P2);
    conv_k<128, 128, 3, 1, 1, 64, 64, 64, 64, 16, 4, 1, false>
        <<<dim3(4, 8, 16), 256, 0, stream>>>(P2, r1aw, nullptr, P3);
    conv1x1_k<128, 128, 4, 0, false, false, true, false>
        <<<dim3(4, 8, 16), 256, 0, stream>>>(P3, r1bw, nullptr, P2, P1);
    conv_k<128, 128, 3, 1, 1, 64, 64, 64, 64, 16, 4, 1, false>
        <<<dim3(4, 8, 16), 256, 0, stream>>>(P1, r2aw, nullptr, P3);
    conv1x1_k<128, 128, 4, 0, false, false, true, false>
        <<<dim3(4, 8, 16), 256, 0, stream>>>(P3, r2bw, nullptr, P1, P2);
    conv1x1_k<128, 64, 2, 2, true, true, false, true>
        <<<dim3(8, 4, 16), 256, 0, stream>>>(P2, e4w, e4b, nullptr, Z);

    // ---- residual VQ ----
    rvq_k<<<1024, 128, 0, stream>>>(Z, cbs, NRM, Q, out_idx, LACC);
    fin_k<<<1, 64, 0, stream>>>(LACC, out_loss);

    // ---- decoder ----
    conv_k<64, 128, 3, 1, 1, 64, 64, 64, 64, 16, 4, 2, true>
        <<<dim3(4, 8, 16), 256, 0, stream>>>(Q, d1w, d1b, P1);
    conv_k<128, 128, 3, 1, 1, 64, 64, 64, 64, 16, 4, 1, false>
        <<<dim3(4, 8, 16), 256, 0, stream>>>(P1, dr1aw, nullptr, P2);
    conv1x1_k<128, 128, 4, 0, false, false, true, false>
        <<<dim3(4, 8, 16), 256, 0, stream>>>(P2, dr1bw, nullptr, P1, P3);
    conv_k<128, 128, 3, 1, 1, 64, 64, 64, 64, 16, 4, 1, false>
        <<<dim3(4, 8, 16), 256, 0, stream>>>(P3, dr2aw, nullptr, P2);
    conv1x1_k<128, 128, 4, 0, false, false, true, false>
        <<<dim3(4, 8, 16), 256, 0, stream>>>(P2, dr2bw, nullptr, P3, P1);
    convt_k<128, 64, 16, 64, 8, 2, true>
        <<<dim3(16, 4, 16), 256, 0, stream>>>(P1, dt1w, dt1b, BIG);
    convt_k<64, 4, 4, 128, 16, 1, false>
        <<<dim3(64, 1, 16), 256, 0, stream>>>(BIG, dt2w, dt2b, out_recons);
}

// Round 13
// 2843.408 us; speedup vs baseline: 1.3532x; 1.0244x over previous
//
#include <hip/hip_runtime.h>
#include <cstddef>

// ---------------------------------------------------------------------------
// RQ-VAE forward on MI355X. Round 13: R8 config restored (e2 NPY=2) + e1
// NPY=2 (keeps (256,4) bounds and 8 blocks/CU -- the R12 e2 regression came
// from dropping to 2 blocks/CU on a strided layer, which e1 avoids).
// rvq untouched at its validated 537us plateau.
// ---------------------------------------------------------------------------

template<int ACT> __device__ __forceinline__ float actf(float v) {
    if constexpr (ACT == 1) return v > 0.f ? v : 0.f;            // relu
    else if constexpr (ACT == 2) return v > 0.f ? v : 0.01f * v; // leaky relu
    else return v;
}
__device__ __forceinline__ float lrelu_in(float v) { return v > 0.f ? v : 0.01f * v; }

// ---------------------------------------------------------------------------
// Direct conv: thread = NPY vertical output pixels x 16 output channels.
// (validated R8)
// ---------------------------------------------------------------------------
template<int CIN, int COUT, int K, int S, int P, int HIN, int WIN, int HOUT, int WOUT,
         int ICC, int NPY, int ACT, bool BIAS>
__launch_bounds__(256, (NPY >= 4 ? 2 : 4))
__global__ void conv_k(const float* __restrict__ in, const float* __restrict__ w,
                       const float* __restrict__ bias, float* __restrict__ out)
{
    constexpr int K2 = K * K;
    constexpr int NR = S * (NPY - 1) + K;
    constexpr int BH = 16 * NPY;
    __shared__ float sw[ICC * K2 * 16];
    const int tid = threadIdx.x;
    const int tx = tid & 15, ty = tid >> 4;
    constexpr int TW = WOUT / 16;
    const int bx = blockIdx.x % TW, by = blockIdx.x / TW;
    const int ox = bx * 16 + tx;
    const int oy0 = by * BH + ty * NPY;
    const int oc0 = blockIdx.y * 16;
    const int n = blockIdx.z;
    const int ix0 = ox * S - P, iy0 = oy0 * S - P;

    int ro[NR]; float mr[NR];
#pragma unroll
    for (int r = 0; r < NR; ++r) {
        const int iy = iy0 + r;
        const bool v = (iy >= 0) && (iy < HIN);
        ro[r] = v ? iy * WIN : 0;
        mr[r] = v ? 1.f : 0.f;
    }
    int co[K]; float mc[K];
#pragma unroll
    for (int c = 0; c < K; ++c) {
        const int ix = ix0 + c;
        const bool v = (ix >= 0) && (ix < WIN);
        co[c] = v ? ix : 0;
        mc[c] = v ? 1.f : 0.f;
    }

    float acc[NPY][16];
#pragma unroll
    for (int py = 0; py < NPY; ++py)
#pragma unroll
        for (int j = 0; j < 16; ++j) acc[py][j] = 0.f;

    for (int ic0 = 0; ic0 < CIN; ic0 += ICC) {
        __syncthreads();
        for (int t = tid; t < ICC * K2 * 16; t += 256) {
            int oc_l = t & 15, r = t >> 4, k = r % K2, ic_l = r / K2;
            sw[(ic_l * K2 + k) * 16 + oc_l] =
                w[((size_t)(oc0 + oc_l) * CIN + ic0 + ic_l) * K2 + k];
        }
        __syncthreads();
#pragma unroll 1
        for (int ic_l = 0; ic_l < ICC; ++ic_l) {
            const float* ip = in + (size_t)(n * CIN + ic0 + ic_l) * HIN * WIN;
            float patch[NR][K];
#pragma unroll
            for (int r = 0; r < NR; ++r)
#pragma unroll
                for (int c = 0; c < K; ++c)
                    patch[r][c] = ip[ro[r] + co[c]] * (mr[r] * mc[c]);
            const float* swp = &sw[ic_l * K2 * 16];
#pragma unroll
            for (int ky = 0; ky < K; ++ky) {
#pragma unroll
                for (int kx = 0; kx < K; ++kx) {
                    const float4* wp = (const float4*)&swp[(ky * K + kx) * 16];
                    float4 w0 = wp[0], w1 = wp[1], w2 = wp[2], w3 = wp[3];
#pragma unroll
                    for (int py = 0; py < NPY; ++py) {
                        const float v = patch[py * S + ky][kx];
                        acc[py][0]  = fmaf(w0.x, v, acc[py][0]);
                        acc[py][1]  = fmaf(w0.y, v, acc[py][1]);
                        acc[py][2]  = fmaf(w0.z, v, acc[py][2]);
                        acc[py][3]  = fmaf(w0.w, v, acc[py][3]);
                        acc[py][4]  = fmaf(w1.x, v, acc[py][4]);
                        acc[py][5]  = fmaf(w1.y, v, acc[py][5]);
                        acc[py][6]  = fmaf(w1.z, v, acc[py][6]);
                        acc[py][7]  = fmaf(w1.w, v, acc[py][7]);
                        acc[py][8]  = fmaf(w2.x, v, acc[py][8]);
                        acc[py][9]  = fmaf(w2.y, v, acc[py][9]);
                        acc[py][10] = fmaf(w2.z, v, acc[py][10]);
                        acc[py][11] = fmaf(w2.w, v, acc[py][11]);
                        acc[py][12] = fmaf(w3.x, v, acc[py][12]);
                        acc[py][13] = fmaf(w3.y, v, acc[py][13]);
                        acc[py][14] = fmaf(w3.z, v, acc[py][14]);
                        acc[py][15] = fmaf(w3.w, v, acc[py][15]);
                    }
                }
            }
        }
    }
#pragma unroll
    for (int py = 0; py < NPY; ++py) {
#pragma unroll
        for (int j = 0; j < 16; ++j) {
            float r = acc[py][j];
            if (BIAS) r += bias[oc0 + j];
            r = actf<ACT>(r);
            out[((size_t)(n * COUT + oc0 + j) * HOUT + oy0 + py) * WOUT + ox] = r;
        }
    }
}

// ---------------------------------------------------------------------------
// 1x1 conv over 64x64 maps (HW=4096), NPX pixels per thread. (validated R8)
// ---------------------------------------------------------------------------
template<int CIN, int COUT, int NPX, int ACT, bool BIAS, bool INL, bool RESID, bool TOK>
__launch_bounds__(256, 3)
__global__ void conv1x1_k(const float* __restrict__ in, const float* __restrict__ w,
                          const float* __restrict__ bias, const float* __restrict__ resid,
                          float* __restrict__ out)
{
    constexpr int HW = 4096;
    __shared__ float sw[16 * CIN];
    const int tid = threadIdx.x;
    const int base = blockIdx.x * (256 * NPX) + tid;
    const int oc0 = blockIdx.y * 16;
    const int n = blockIdx.z;

    for (int t = tid; t < 16 * CIN; t += 256) {
        int oc_l = t & 15, ic = t >> 4;
        sw[ic * 16 + oc_l] = w[(size_t)(oc0 + oc_l) * CIN + ic];
    }
    __syncthreads();

    float acc[NPX][16];
#pragma unroll
    for (int p = 0; p < NPX; ++p)
#pragma unroll
        for (int j = 0; j < 16; ++j) acc[p][j] = 0.f;

    const float* ip = in + (size_t)n * CIN * HW;
#pragma unroll 2
    for (int ic = 0; ic < CIN; ++ic) {
        float v[NPX];
#pragma unroll
        for (int p = 0; p < NPX; ++p) {
            float t = ip[(size_t)ic * HW + base + 256 * p];
            if (INL) t = lrelu_in(t);
            v[p] = t;
        }
        const float4* wp = (const float4*)&sw[ic * 16];
#pragma unroll
        for (int q4 = 0; q4 < 4; ++q4) {
            const float4 wv = wp[q4];
#pragma unroll
            for (int p = 0; p < NPX; ++p) {
                acc[p][q4 * 4 + 0] = fmaf(wv.x, v[p], acc[p][q4 * 4 + 0]);
                acc[p][q4 * 4 + 1] = fmaf(wv.y, v[p], acc[p][q4 * 4 + 1]);
                acc[p][q4 * 4 + 2] = fmaf(wv.z, v[p], acc[p][q4 * 4 + 2]);
                acc[p][q4 * 4 + 3] = fmaf(wv.w, v[p], acc[p][q4 * 4 + 3]);
            }
        }
    }
#pragma unroll
    for (int p = 0; p < NPX; ++p) {
        const int pix = base + 256 * p;
#pragma unroll
        for (int j = 0; j < 16; ++j) {
            float r = acc[p][j];
            if (BIAS) r += bias[oc0 + j];
            r = actf<ACT>(r);
            if (RESID) r += resid[((size_t)(n * COUT + oc0 + j)) * HW + pix];
            if (TOK)
                out[((size_t)n * HW + pix) * COUT + oc0 + j] = r;
            else
                out[((size_t)(n * COUT + oc0 + j)) * HW + pix] = r;
        }
    }
}

// ---------------------------------------------------------------------------
// ConvTranspose2d k=4 s=2 p=1, parity decomposition. (validated R2/R5/R8)
// ---------------------------------------------------------------------------
template<int CIN, int COUT, int OCT, int HIN, int ICC, int ACT, bool INL>
__launch_bounds__(256, 3)
__global__ void convt_k(const float* __restrict__ in, const float* __restrict__ w,
                        const float* __restrict__ bias, float* __restrict__ out)
{
    constexpr int WIN = HIN, HOUT = 2 * HIN, WOUT = 2 * HIN;
    __shared__ float sw[ICC * 16 * OCT];
    const int tid = threadIdx.x;
    const int tx = tid & 15, ty = tid >> 4;
    constexpr int TBW = WOUT / 32;
    const int bx = blockIdx.x % TBW, by = blockIdx.x / TBW;
    const int A = by * 16 + ty;
    const int C = bx * 16 + tx;
    const int oc0 = blockIdx.y * OCT;
    const int n = blockIdx.z;

    int offs[9]; float msk[9];
#pragma unroll
    for (int dy = 0; dy < 3; ++dy) {
#pragma unroll
        for (int dx = 0; dx < 3; ++dx) {
            const int iy = A - 1 + dy, ix = C - 1 + dx;
            const bool v = (iy >= 0) && (iy < HIN) && (ix >= 0) && (ix < WIN);
            offs[dy * 3 + dx] = v ? iy * WIN + ix : 0;
            msk[dy * 3 + dx] = v ? 1.f : 0.f;
        }
    }

    float acc[4 * OCT];
#pragma unroll
    for (int j = 0; j < 4 * OCT; ++j) acc[j] = 0.f;

    for (int ic0 = 0; ic0 < CIN; ic0 += ICC) {
        __syncthreads();
        for (int t = tid; t < ICC * 16 * OCT; t += 256) {
            int oc_l = t % OCT, r = t / OCT, k = r & 15, ic_l = r >> 4;
            sw[(ic_l * 16 + k) * OCT + oc_l] =
                w[((size_t)(ic0 + ic_l) * COUT + oc0 + oc_l) * 16 + k];
        }
        __syncthreads();
#pragma unroll 1
        for (int ic_l = 0; ic_l < ICC; ++ic_l) {
            const float* ip = in + (size_t)(n * CIN + ic0 + ic_l) * HIN * WIN;
            float in9[9];
#pragma unroll
            for (int j = 0; j < 9; ++j) {
                float v = ip[offs[j]] * msk[j];
                if (INL) v = lrelu_in(v);
                in9[j] = v;
            }
#pragma unroll
            for (int ky = 0; ky < 4; ++ky) {
                const int ry = (ky + 1) & 1;
                const int dy = 2 - ((ky + 1) >> 1);
#pragma unroll
                for (int kx = 0; kx < 4; ++kx) {
                    const int rx = (kx + 1) & 1;
                    const int dx = 2 - ((kx + 1) >> 1);
                    const float v = in9[dy * 3 + dx];
                    const int po = ry * 2 + rx;
                    const float4* wp = (const float4*)&sw[(ic_l * 16 + ky * 4 + kx) * OCT];
#pragma unroll
                    for (int q4 = 0; q4 < OCT / 4; ++q4) {
                        float4 wv = wp[q4];
                        acc[po * OCT + q4 * 4 + 0] = fmaf(wv.x, v, acc[po * OCT + q4 * 4 + 0]);
                        acc[po * OCT + q4 * 4 + 1] = fmaf(wv.y, v, acc[po * OCT + q4 * 4 + 1]);
                        acc[po * OCT + q4 * 4 + 2] = fmaf(wv.z, v, acc[po * OCT + q4 * 4 + 2]);
                        acc[po * OCT + q4 * 4 + 3] = fmaf(wv.w, v, acc[po * OCT + q4 * 4 + 3]);
                    }
                }
            }
        }
    }
#pragma unroll
    for (int po = 0; po < 4; ++po) {
        const int ry = po >> 1, rx = po & 1;
        const int oy = 2 * A + ry, ox = 2 * C + rx;
#pragma unroll
        for (int j = 0; j < OCT; ++j) {
            float r = acc[po * OCT + j] + bias[oc0 + j];
            r = actf<ACT>(r);
            out[((size_t)(n * COUT + oc0 + j) * HOUT + oy) * WOUT + ox] = r;
        }
    }
}

// ---------------------------------------------------------------------------
// Codebook norms, precomputed once. (validated R7/R8)
// ---------------------------------------------------------------------------
__global__ void norm_k(const float* __restrict__ cb, float* __restrict__ nrm) {
    const int c = blockIdx.x * 256 + threadIdx.x;   // 0..2047
    const float4* p = (const float4*)(cb + (size_t)c * 64);
    float a0 = 0.f, a1 = 0.f, a2 = 0.f, a3 = 0.f;
#pragma unroll
    for (int i = 0; i < 16; ++i) {
        float4 v = p[i];
        a0 = fmaf(v.x, v.x, a0); a1 = fmaf(v.y, v.y, a1);
        a2 = fmaf(v.z, v.z, a2); a3 = fmaf(v.w, v.w, a3);
    }
    nrm[c] = (a0 + a1) + (a2 + a3);
}

// ---------------------------------------------------------------------------
// Residual VQ: 2 lanes/token, block=128, grid=1024 + norm table. (validated
// R7/R8: ~537us plateau.)
// ---------------------------------------------------------------------------
__launch_bounds__(128)
__global__ void rvq_k(const float* __restrict__ z, const float* __restrict__ cb,
                      const float* __restrict__ nrm,
                      float* __restrict__ q, float* __restrict__ idx_out,
                      float* __restrict__ loss_acc)
{
    __shared__ float scb[128 * 64];
    __shared__ float ssc[128];
    const int tid = threadIdx.x;
    const int h = tid & 1;
    const int tloc = tid >> 1;
    const int t = blockIdx.x * 64 + tloc;

    float zr[32], r[32];
    const float4* zp = (const float4*)(z + (size_t)t * 64 + h * 32);
#pragma unroll
    for (int i = 0; i < 8; ++i) {
        float4 v = zp[i];
        zr[4 * i + 0] = v.x; zr[4 * i + 1] = v.y; zr[4 * i + 2] = v.z; zr[4 * i + 3] = v.w;
        r[4 * i + 0] = v.x;  r[4 * i + 1] = v.y;  r[4 * i + 2] = v.z;  r[4 * i + 3] = v.w;
    }

    for (int s = 0; s < 4; ++s) {
        float s0 = 0.f, s1 = 0.f, s2 = 0.f, s3 = 0.f;
#pragma unroll
        for (int i = 0; i < 32; i += 4) {
            s0 = fmaf(r[i + 0], r[i + 0], s0);
            s1 = fmaf(r[i + 1], r[i + 1], s1);
            s2 = fmaf(r[i + 2], r[i + 2], s2);
            s3 = fmaf(r[i + 3], r[i + 3], s3);
        }
        float sr2 = (s0 + s1) + (s2 + s3);
        sr2 += __shfl_xor(sr2, 1, 64);

        float dmin = 3.4e38f;
        int best = 0;
        for (int pass = 0; pass < 4; ++pass) {
            __syncthreads();
            const float* src = cb + ((size_t)s * 512 + pass * 128) * 64;
            for (int i2 = tid; i2 < 128 * 64 / 4; i2 += 128)
                ((float4*)scb)[i2] = ((const float4*)src)[i2];
            ssc[tid] = nrm[(size_t)s * 512 + pass * 128 + tid];
            __syncthreads();
#pragma unroll 2
            for (int kk = 0; kk < 128; ++kk) {
                const float4* cp = (const float4*)&scb[kk * 64 + h * 32];
                float d0 = 0.f, d1 = 0.f, d2 = 0.f, d3 = 0.f;
#pragma unroll
                for (int i = 0; i < 8; ++i) {
                    float4 c = cp[i];
                    d0 = fmaf(r[4 * i + 0], c.x, d0);
                    d1 = fmaf(r[4 * i + 1], c.y, d1);
                    d2 = fmaf(r[4 * i + 2], c.z, d2);
                    d3 = fmaf(r[4 * i + 3], c.w, d3);
                }
                float dot = (d0 + d1) + (d2 + d3);
                dot += __shfl_xor(dot, 1, 64);
                const float d = fmaf(-2.f, dot, sr2) + ssc[kk];
                if (d < dmin) { dmin = d; best = pass * 128 + kk; }
            }
        }
        float lv = (h == 0) ? dmin : 0.f;
#pragma unroll
        for (int off = 32; off; off >>= 1) lv += __shfl_down(lv, off, 64);
        if ((tid & 63) == 0) atomicAdd(&loss_acc[s], lv);

        if (h == 0) idx_out[(size_t)t * 4 + s] = (float)best;

        const float4* cbest = (const float4*)(cb + ((size_t)s * 512 + best) * 64 + h * 32);
#pragma unroll
        for (int i = 0; i < 8; ++i) {
            float4 c = cbest[i];
            r[4 * i + 0] -= c.x; r[4 * i + 1] -= c.y;
            r[4 * i + 2] -= c.z; r[4 * i + 3] -= c.w;
        }
    }
    const int n = t >> 12, pix = t & 4095;
    float* qp = q + (size_t)n * 64 * 4096 + pix;
#pragma unroll
    for (int i = 0; i < 32; ++i)
        qp[(size_t)(h * 32 + i) * 4096] = zr[i] - r[i];
}

__global__ void init_k(float* loss_acc) {
    if (threadIdx.x < 4) loss_acc[threadIdx.x] = 0.f;
}
__global__ void fin_k(const float* __restrict__ loss_acc, float* __restrict__ out_loss) {
    if (threadIdx.x < 4)
        out_loss[threadIdx.x] = loss_acc[threadIdx.x] * (0.25f / 4194304.f); // BETA/(N*D)
}

// ---------------------------------------------------------------------------
extern "C" void kernel_launch(void* const* d_in, const int* in_sizes, int n_in,
                              void* d_out, int out_size, void* d_ws, size_t ws_size,
                              hipStream_t stream)
{
    const float* x    = (const float*)d_in[0];
    const float* e1w  = (const float*)d_in[1];  const float* e1b = (const float*)d_in[2];
    const float* e2w  = (const float*)d_in[3];  const float* e2b = (const float*)d_in[4];
    const float* e3w  = (const float*)d_in[5];  const float* e3b = (const float*)d_in[6];
    const float* r1aw = (const float*)d_in[7];  const float* r1bw = (const float*)d_in[8];
    const float* r2aw = (const float*)d_in[9];  const float* r2bw = (const float*)d_in[10];
    const float* e4w  = (const float*)d_in[11]; const float* e4b = (const float*)d_in[12];
    const float* cbs  = (const float*)d_in[13];
    const float* d1w  = (const float*)d_in[14]; const float* d1b = (const float*)d_in[15];
    const float* dr1aw= (const float*)d_in[16]; const float* dr1bw = (const float*)d_in[17];
    const float* dr2aw= (const float*)d_in[18]; const float* dr2bw = (const float*)d_in[19];
    const float* dt1w = (const float*)d_in[20]; const float* dt1b = (const float*)d_in[21];
    const float* dt2w = (const float*)d_in[22]; const float* dt2b = (const float*)d_in[23];

    float* out = (float*)d_out;
    float* ws  = (float*)d_ws;

    float* BIG = ws;                    // 16.78M floats (e1 out / dt1 out)
    float* P2  = BIG;
    float* P3  = BIG + 8388608;
    float* P1  = ws + 16777216;
    float* Z   = ws + 25165824;
    float* Q   = ws + 29360128;
    float* LACC= ws + 33554432;         // 4 floats
    float* NRM = ws + 33554448;         // 2048 floats

    float* out_recons = out;                    // 16*4*256*256 = 4194304
    float* out_idx    = out + 4194304;          // 16*64*64*4   = 262144
    float* out_loss   = out + 4194304 + 262144; // 4

    init_k<<<1, 64, 0, stream>>>(LACC);
    norm_k<<<8, 256, 0, stream>>>(cbs, NRM);

    // ---- encoder ----
    // e1: NPY=2 -> BH=32, grid (TW=8 x 128/32=4 -> 32, 4, 16) = 2048 blocks
    conv_k<4, 64, 4, 2, 1, 256, 256, 128, 128, 4, 2, 2, true>
        <<<dim3(32, 4, 16), 256, 0, stream>>>(x, e1w, e1b, BIG);
    // e2: back to R8 NPY=2 (4 blocks/CU matters for the strided loads)
    conv_k<64, 128, 4, 2, 1, 128, 128, 64, 64, 16, 2, 2, true>
        <<<dim3(8, 8, 16), 256, 0, stream>>>(BIG, e2w, e2b, P1);
    conv_k<128, 128, 3, 1, 1, 64, 64, 64, 64, 16, 4, 2, true>
        <<<dim3(4, 8, 16), 256, 0, stream>>>(P1, e3w, e3b, P2);
    conv_k<128, 128, 3, 1, 1, 64, 64, 64, 64, 16, 4, 1, false>
        <<<dim3(4, 8, 16), 256, 0, stream>>>(P2, r1aw, nullptr, P3);
    conv1x1_k<128, 128, 4, 0, false, false, true, false>
        <<<dim3(4, 8, 16), 256, 0, stream>>>(P3, r1bw, nullptr, P2, P1);
    conv_k<128, 128, 3, 1, 1, 64, 64, 64, 64, 16, 4, 1, false>
        <<<dim3(4, 8, 16), 256, 0, stream>>>(P1, r2aw, nullptr, P3);
    conv1x1_k<128, 128, 4, 0, false, false, true, false>
        <<<dim3(4, 8, 16), 256, 0, stream>>>(P3, r2bw, nullptr, P1, P2);
    conv1x1_k<128, 64, 2, 2, true, true, false, true>
        <<<dim3(8, 4, 16), 256, 0, stream>>>(P2, e4w, e4b, nullptr, Z);

    // ---- residual VQ ----
    rvq_k<<<1024, 128, 0, stream>>>(Z, cbs, NRM, Q, out_idx, LACC);
    fin_k<<<1, 64, 0, stream>>>(LACC, out_loss);

    // ---- decoder ----
    conv_k<64, 128, 3, 1, 1, 64, 64, 64, 64, 16, 4, 2, true>
        <<<dim3(4, 8, 16), 256, 0, stream>>>(Q, d1w, d1b, P1);
    conv_k<128, 128, 3, 1, 1, 64, 64, 64, 64, 16, 4, 1, false>
        <<<dim3(4, 8, 16), 256, 0, stream>>>(P1, dr1aw, nullptr, P2);
    conv1x1_k<128, 128, 4, 0, false, false, true, false>
        <<<dim3(4, 8, 16), 256, 0, stream>>>(P2, dr1bw, nullptr, P1, P3);
    conv_k<128, 128, 3, 1, 1, 64, 64, 64, 64, 16, 4, 1, false>
        <<<dim3(4, 8, 16), 256, 0, stream>>>(P3, dr2aw, nullptr, P2);
    conv1x1_k<128, 128, 4, 0, false, false, true, false>
        <<<dim3(4, 8, 16), 256, 0, stream>>>(P2, dr2bw, nullptr, P3, P1);
    convt_k<128, 64, 16, 64, 8, 2, true>
        <<<dim3(16, 4, 16), 256, 0, stream>>>(P1, dt1w, dt1b, BIG);
    convt_k<64, 4, 4, 128, 16, 1, false>
        <<<dim3(64, 1, 16), 256, 0, stream>>>(BIG, dt2w, dt2b, out_recons);
}